// Round 10
// baseline (115.781 us; speedup 1.0000x reference)
//
#include <hip/hip_runtime.h>
#include <math.h>

#define NT 365
#define NS 2048
#define NH 64
#define NG 128
#define NW 513      // nh*8+1
#define WSTR 520    // padded row stride for w buffer
#define FTR 368     // padded per-pair forcing row length (t-slots)

typedef float v2f __attribute__((ext_vector_type(2)));

__device__ __forceinline__ float sigmoidf_(float x) {
    return 1.0f / (1.0f + __expf(-x));
}
__device__ __forceinline__ v2f vmin2(v2f a, v2f b) {
    v2f r; r.x = fminf(a.x, b.x); r.y = fminf(a.y, b.y); return r;
}
__device__ __forceinline__ v2f vmax0(v2f a) {
    v2f r; r.x = fmaxf(a.x, 0.0f); r.y = fmaxf(a.y, 0.0f); return r;
}

// ---------------- Kernel P: fused prep = gemm (blocks 0..255) + forcing ------
// forcing (blocks 256..319): writes PAIR-INTERLEAVED transposed rows:
// fpair[p][t] = {PsA,PsB,PlA,PlB,EA,EB,TaRA,TaRB} (32 B) for sites 2p,2p+1 —
// the scan's two dwordx4 loads then land as pre-packed v2f register pairs.
__global__ __launch_bounds__(256) void prep_kernel(const float* __restrict__ xc,
                                                   const float* __restrict__ Wm,
                                                   const float* __restrict__ bv,
                                                   float* __restrict__ w,
                                                   const float* __restrict__ x,
                                                   float* __restrict__ f) {
    __shared__ float xcs[64][132];  // +4 pad: breaks bank conflict on column reads
    __shared__ float Wsh[64][132];
    const int tid = threadIdx.x;

    if (blockIdx.x >= 256) {
        // ---- forcing branch: 16 pairs x 16 phases per block ----
        const int b = blockIdx.x - 256;        // 0..63
        const int p = b * 16 + (tid >> 4);     // pair 0..1023
        const int phase = tid & 15;
        const float4* xp = (const float4*)x;
        float4* fpo = (float4*)(f + (size_t)p * (FTR * 8));
        for (int tt = phase; tt < NT; tt += 16) {
            float4 vA = xp[(size_t)tt * NS + 2 * p];
            float4 vB = xp[(size_t)tt * NS + 2 * p + 1];
            float PsA, PlA, TaRA, PsB, PlB, TaRB;
            {
                float P = vA.x, T1 = vA.z, T2 = vA.w;
                float Ta = 0.5f * (T1 + T2);
                float rP;
                if (T2 <= 0.0f)       rP = 0.0f;   // mask0 wins (ref order)
                else if (T1 >= 0.0f)  rP = 1.0f;
                else                  rP = 1.0f - acosf((T1 + T2) / (T2 - T1)) * (1.0f / 3.1415f);
                PsA = (1.0f - rP) * P; PlA = rP * P; TaRA = fmaxf(Ta, 0.0f);
            }
            {
                float P = vB.x, T1 = vB.z, T2 = vB.w;
                float Ta = 0.5f * (T1 + T2);
                float rP;
                if (T2 <= 0.0f)       rP = 0.0f;
                else if (T1 >= 0.0f)  rP = 1.0f;
                else                  rP = 1.0f - acosf((T1 + T2) / (T2 - T1)) * (1.0f / 3.1415f);
                PsB = (1.0f - rP) * P; PlB = rP * P; TaRB = fmaxf(Ta, 0.0f);
            }
            fpo[tt * 2]     = make_float4(PsA, PsB, PlA, PlB);
            fpo[tt * 2 + 1] = make_float4(vA.y, vB.y, TaRA, TaRB);
        }
        return;
    }

    // ---- gemm branch: w = xc @ W^T + b; 64x64 tile, K=128 in LDS ----
    const int sTile = (blockIdx.x >> 3) * 64;                // 32 s-tiles
    const int by = blockIdx.x & 7;
    const int jt = (by >= 2) ? by + 1 : by;                  // skip unused j-tile 2
    const int jTile = jt * 64;

    for (int i = 0; i < 8; i++) {
        int f4  = tid + i * 256;
        int row = f4 >> 5;
        int c4  = (f4 & 31) * 4;
        float4 v = ((const float4*)(xc + (size_t)(sTile + row) * NG))[f4 & 31];
        xcs[row][c4] = v.x; xcs[row][c4 + 1] = v.y; xcs[row][c4 + 2] = v.z; xcs[row][c4 + 3] = v.w;
        int jr = jTile + row;
        float4 wv = make_float4(0.f, 0.f, 0.f, 0.f);
        if (jr < NW) wv = ((const float4*)(Wm + (size_t)jr * NG))[f4 & 31];
        Wsh[row][c4] = wv.x; Wsh[row][c4 + 1] = wv.y; Wsh[row][c4 + 2] = wv.z; Wsh[row][c4 + 3] = wv.w;
    }
    __syncthreads();

    const int tx = tid & 15, ty = tid >> 4;
    float acc[4][4] = {};
#pragma unroll 4
    for (int k = 0; k < 128; k++) {
        float a0 = xcs[ty][k], a1 = xcs[ty + 16][k], a2 = xcs[ty + 32][k], a3 = xcs[ty + 48][k];
        float b0 = Wsh[tx][k], b1 = Wsh[tx + 16][k], b2 = Wsh[tx + 32][k], b3 = Wsh[tx + 48][k];
        acc[0][0] += a0 * b0; acc[0][1] += a0 * b1; acc[0][2] += a0 * b2; acc[0][3] += a0 * b3;
        acc[1][0] += a1 * b0; acc[1][1] += a1 * b1; acc[1][2] += a1 * b2; acc[1][3] += a1 * b3;
        acc[2][0] += a2 * b0; acc[2][1] += a2 * b1; acc[2][2] += a2 * b2; acc[2][3] += a2 * b3;
        acc[3][0] += a3 * b0; acc[3][1] += a3 * b1; acc[3][2] += a3 * b2; acc[3][3] += a3 * b3;
    }
#pragma unroll
    for (int i = 0; i < 4; i++) {
        int s = sTile + ty + 16 * i;
#pragma unroll
        for (int j = 0; j < 4; j++) {
            int jj = jTile + tx + 16 * j;
            if (jj < NW) w[(size_t)s * WSTR + jj] = acc[i][j] + bv[jj];
        }
    }
}

// ---------------- Kernel C (packed): scan, TWO sites per LANE via v2f --------
// All mul/add/fma in the step body are <2 x float> -> v_pk_{fma,add,mul}_f32;
// min/max scalarize (no pk form). 1024 waves (1/SIMD), ~30 instr per 2-site
// step vs 46 scalar. Per-step ds_write_b64 into [64][66] tile; TRRED every 32
// steps via b64 reads + pk adds. 16-deep rolling prefetch (pair rows are
// contiguous: saddr + laundered voff + imm; pad slots feed masked steps only).
__global__ __launch_bounds__(256, 1) void scan_pk_kernel(const float* __restrict__ fx,
                                                         const float* __restrict__ w,
                                                         float* __restrict__ Y) {
    __shared__ float ybuf[4][64][66];   // 67,584 B -> 1 block/CU
    const int wave = threadIdx.x >> 6;
    const int lane = threadIdx.x & 63;
    const int pair = blockIdx.x * 4 + wave;     // 0..1023
    const int sA = pair * 2;
    const float* wrA = w + (size_t)sA * WSTR;
    const float* wrB = wrA + WSTR;

    // ---- packed gate parameters (lane = hidden unit; .x = site A, .y = B) ----
    v2f gm  = { __expf(wrA[lane]) + 1.0f,        __expf(wrB[lane]) + 1.0f };
    v2f geN = { -2.0f * sigmoidf_(wrA[64 + lane]), -2.0f * sigmoidf_(wrB[64 + lane]) };
    v2f k0  = { sigmoidf_(wrA[192 + lane]),      sigmoidf_(wrB[192 + lane]) };
    v2f w4  = { wrA[256 + lane],                 wrB[256 + lane] };
    v2f k1  = { sigmoidf_(w4.x),                 sigmoidf_(w4.y) };
    v2f k2  = { sigmoidf_(wrA[320 + lane]),      sigmoidf_(wrB[320 + lane]) };
    v2f gl  = { __expf(wrA[384 + lane]),         __expf(wrB[384 + lane]) };
    v2f kb  = { sigmoidf_(wrA[448 + lane]) * 0.1f, sigmoidf_(wrB[448 + lane]) * 0.1f };
    float wlA = wrA[512], wlB = wrB[512];
    float qbA = fmaxf(wlA, 0.0f) * (1.0f / NH), qbB = fmaxf(wlB, 0.0f) * (1.0f / NH);
    v2f vi  = { sigmoidf_(wlA),                  sigmoidf_(wlB) };

    // softmax over lanes -> ga (per component; setup only)
    float mA = w4.x, mB = w4.y;
#pragma unroll
    for (int off = 32; off; off >>= 1) {
        mA = fmaxf(mA, __shfl_xor(mA, off));
        mB = fmaxf(mB, __shfl_xor(mB, off));
    }
    float exA = __expf(w4.x - mA), exB = __expf(w4.y - mB);
    float smA = exA, smB = exB;
#pragma unroll
    for (int off = 32; off; off >>= 1) {
        smA += __shfl_xor(smA, off);
        smB += __shfl_xor(smB, off);
    }
    v2f ga = { exA / smA, exB / smB };

    // folded coefficients (all v2f)
    v2f one = { 1.0f, 1.0f };
    v2f c0   = k0 * ga;
    v2f c1   = k1 * (one - kb) * ga;
    v2f c2   = k2 * ga;
    v2f k0c  = one - k0;
    v2f k2c  = one - k2;
    v2f glN  = -gl;
    v2f viC  = one - vi;
    v2f k1kb = k1 * kb;
    v2f k1N  = -k1;

    v2f S0 = {0.f, 0.f}, H0 = {0.f, 0.f}, H1 = {0.f, 0.f}, H2 = {0.f, 0.f};

    const char* fB = (const char*)fx;               // uniform SGPR base
    unsigned voff = (unsigned)pair * (FTR * 32u);   // pair row start (bytes)
    asm volatile("" : "+v"(voff));

    float4 va[16], vb[16];                          // va={PsA,PsB,PlA,PlB}, vb={EA,EB,TaA,TaB}
#pragma unroll
    for (int b = 0; b < 16; b++) {
        va[b] = *(const float4*)(fB + voff + b * 32);
        vb[b] = *(const float4*)(fB + voff + b * 32 + 16);
    }

    float* wp = &ybuf[wave][lane][0];                             // write row h=lane
    const float* rp = &ybuf[wave][(lane >> 5) << 5][(lane & 31) * 2]; // read col pair

#define STEP_PK(v1, v2, tl)                                                    \
    {                                                                          \
        v2f Ps = {v1.x, v1.y}, Pl = {v1.z, v1.w};                              \
        v2f E  = {v2.x, v2.y}, Ta = {v2.z, v2.w};                              \
        v2f S  = S0 + Ps;                                                      \
        v2f Sm = vmin2(S0, gm * Ta);                                           \
        S0 = S - Sm;                                                           \
        v2f G1 = vmax0(H1 + Sm + (E * geN + Pl * vi));                         \
        v2f G0 = vmax0(H0 + G1 + (Pl * viC + glN));                            \
        v2f m1 = vmin2(G1, gl);                                                \
        v2f G2 = m1 * k1kb + H2;                                               \
        *(v2f*)&wp[2 * (tl)] = G0 * c0 + (m1 * c1 + G2 * c2);                  \
        H0 = G0 * k0c;                                                         \
        H1 = vmin2(m1 * k1N + G1, gl);                                         \
        H2 = G2 * k2c;                                                         \
    }

#define TRRED_PK(t0)                                                           \
    {                                                                          \
        v2f a0 = {0.f,0.f}, a1 = {0.f,0.f}, a2 = {0.f,0.f}, a3 = {0.f,0.f};    \
        _Pragma("unroll")                                                      \
        for (int j = 0; j < 32; j += 4) {                                      \
            a0 += *(const v2f*)&rp[(size_t)j * 66];                            \
            a1 += *(const v2f*)&rp[(size_t)(j + 1) * 66];                      \
            a2 += *(const v2f*)&rp[(size_t)(j + 2) * 66];                      \
            a3 += *(const v2f*)&rp[(size_t)(j + 3) * 66];                      \
        }                                                                      \
        v2f part = (a0 + a1) + (a2 + a3);                                      \
        float fx_ = part.x + __shfl_xor(part.x, 32);                           \
        float fy_ = part.y + __shfl_xor(part.y, 32);                           \
        int t = (t0) + (lane & 31);                                            \
        if (lane < 32 && t < NT) {                                             \
            Y[(size_t)t * NS + sA]     = fx_ + qbA;                            \
            Y[(size_t)t * NS + sA + 1] = fy_ + qbB;                            \
        }                                                                      \
    }

    // superblocks 0..10: prefetch t = sb*32 + tl + 16; max = 367 <= FTR-1
    // (pad reads land in slots consumed only by masked-out steps t>=365).
    for (int sb = 0; sb < 11; ++sb) {
        const char* fs = fB + sb * (32 * 32);       // uniform scalar advance
#pragma unroll
        for (int tl = 0; tl < 32; ++tl) {
            float4 v1 = va[tl & 15], v2 = vb[tl & 15];
            va[tl & 15] = *(const float4*)(fs + voff + (tl + 16) * 32);
            vb[tl & 15] = *(const float4*)(fs + voff + (tl + 16) * 32 + 16);
            STEP_PK(v1, v2, tl);
        }
        TRRED_PK(sb * 32);
    }
    // tail superblock (t0=352): steps 352..367 consume slots prefetched in
    // sb=10 (352..367); steps 368..383 reuse stale slots — stores masked.
    {
#pragma unroll
        for (int tl = 0; tl < 32; ++tl) {
            float4 v1 = va[tl & 15], v2 = vb[tl & 15];
            STEP_PK(v1, v2, tl);
        }
        TRRED_PK(352);
    }
#undef STEP_PK
#undef TRRED_PK
}

// ---------------- fallback scalar scan (ws too small; reads raw x) -----------
__global__ __launch_bounds__(256) void scan_kernel_raw(const float* __restrict__ fx,
                                                       const float* __restrict__ w,
                                                       float* __restrict__ Y) {
    __shared__ float ybuf[4][64][33];
    const int wave = threadIdx.x >> 6;
    const int lane = threadIdx.x & 63;
    const int s = blockIdx.x * 4 + wave;
    const float* wr = w + (size_t)s * WSTR;

    float gm = __expf(wr[lane]) + 1.0f;
    float geN = -2.0f * sigmoidf_(wr[64 + lane]);
    float k0 = sigmoidf_(wr[192 + lane]);
    float w4 = wr[256 + lane];
    float k1 = sigmoidf_(w4);
    float k2 = sigmoidf_(wr[320 + lane]);
    float gl = __expf(wr[384 + lane]);
    float kb = sigmoidf_(wr[448 + lane]) * 0.1f;
    float wl = wr[512];
    float qb = fmaxf(wl, 0.0f) * (1.0f / (float)NH);
    float vi = sigmoidf_(wl);

    float m = w4;
#pragma unroll
    for (int off = 32; off; off >>= 1) m = fmaxf(m, __shfl_xor(m, off));
    float ex = __expf(w4 - m);
    float sum = ex;
#pragma unroll
    for (int off = 32; off; off >>= 1) sum += __shfl_xor(sum, off);
    float ga = ex / sum;

    float c0 = k0 * ga, c1 = k1 * (1.0f - kb) * ga, c2 = k2 * ga;
    float k0c = 1.0f - k0, k2c = 1.0f - k2, glN = -gl, viC = 1.0f - vi;
    float k1kb = k1 * kb, k1N = -k1;
    float S0 = 0.f, H0 = 0.f, H1 = 0.f, H2 = 0.f;

    unsigned voff = (unsigned)s * 16u;
    asm volatile("" : "+v"(voff));
    const char* fB = (const char*)fx;

    float* wp = &ybuf[wave][lane][0];
    const float* rp = &ybuf[wave][(lane >> 5) << 5][lane & 31];

    for (int sb = 0; sb < 12; ++sb) {
        const int t0 = sb * 32;
        for (int tl = 0; tl < 32; ++tl) {
            int t = t0 + tl; t = t < NT ? t : NT - 1;
            float4 v = *(const float4*)(fB + (size_t)t * (NS * 16) + voff);
            float P = v.x, E = v.y, T1 = v.z, T2 = v.w;
            float Ta = 0.5f * (T1 + T2);
            float rP;
            if (T2 <= 0.0f)      rP = 0.0f;
            else if (T1 >= 0.0f) rP = 1.0f;
            else                 rP = 1.0f - acosf((T1 + T2) / (T2 - T1)) * (1.0f / 3.1415f);
            float Ps = (1.0f - rP) * P, Pl = rP * P, TaR = fmaxf(Ta, 0.0f);
            float S   = S0 + Ps;
            float Sm  = fminf(S0, gm * TaR);
            S0 = S - Sm;
            float G1  = fmaxf(H1 + Sm + fmaf(E, geN, Pl * vi), 0.0f);
            float G0  = fmaxf(H0 + G1 + fmaf(Pl, viC, glN), 0.0f);
            float m1  = fminf(G1, gl);
            float G2  = fmaf(m1, k1kb, H2);
            wp[tl] = fmaf(G0, c0, fmaf(m1, c1, G2 * c2));
            H0 = G0 * k0c;
            H1 = fminf(fmaf(m1, k1N, G1), gl);
            H2 = G2 * k2c;
        }
        float a0 = 0.f, a1 = 0.f, a2 = 0.f, a3 = 0.f;
#pragma unroll
        for (int j = 0; j < 32; j += 4) {
            a0 += rp[(size_t)j * 33];
            a1 += rp[(size_t)(j + 1) * 33];
            a2 += rp[(size_t)(j + 2) * 33];
            a3 += rp[(size_t)(j + 3) * 33];
        }
        float part = (a0 + a1) + (a2 + a3);
        float full = part + __shfl_xor(part, 32);
        int t = t0 + (lane & 31);
        if (lane < 32 && t < NT) Y[(size_t)t * NS + s] = full + qb;
    }
}

extern "C" void kernel_launch(void* const* d_in, const int* in_sizes, int n_in,
                              void* d_out, int out_size, void* d_ws, size_t ws_size,
                              hipStream_t stream) {
    const float* x  = (const float*)d_in[0];   // [NT, NS, 4]
    const float* xc = (const float*)d_in[1];   // [NS, NG]
    const float* Wm = (const float*)d_in[2];   // [NW, NG]
    const float* bv = (const float*)d_in[3];   // [NW]
    float* out = (float*)d_out;                // [NT, NS] fp32

    float* wbuf = (float*)d_ws;                                 // NS*WSTR floats
    size_t wbytes = (size_t)NS * WSTR * sizeof(float);          // 4,259,840 B
    float* fbuf = (float*)((char*)d_ws + wbytes);               // 1024 pair-rows
    size_t need = wbytes + (size_t)(NS / 2) * FTR * 32;         // ~16.3 MB

    if (ws_size >= need) {
        prep_kernel<<<256 + 64, 256, 0, stream>>>(xc, Wm, bv, wbuf, x, fbuf);
        scan_pk_kernel<<<NS / 8, 256, 0, stream>>>(fbuf, wbuf, out);
    } else {
        prep_kernel<<<256, 256, 0, stream>>>(xc, Wm, bv, wbuf, x, fbuf);  // gemm only
        scan_kernel_raw<<<NS / 4, 256, 0, stream>>>(x, wbuf, out);
    }
}

// Round 11
// 106.011 us; speedup vs baseline: 1.0922x; 1.0922x over previous
//
#include <hip/hip_runtime.h>
#include <math.h>

#define NT 365
#define NS 2048
#define NH 64
#define NG 128
#define NW 513      // nh*8+1
#define WSTR 520    // padded row stride for w buffer

__device__ __forceinline__ float sigmoidf_(float x) {
    return 1.0f / (1.0f + __expf(-x));
}

// ---------------- Kernel P: fused prep = gemm (blocks 0..255) + forcing ------
__global__ __launch_bounds__(256) void prep_kernel(const float* __restrict__ xc,
                                                   const float* __restrict__ Wm,
                                                   const float* __restrict__ bv,
                                                   float* __restrict__ w,
                                                   const float* __restrict__ x,
                                                   float* __restrict__ f) {
    __shared__ float xcs[64][132];  // +4 pad: breaks bank conflict on column reads
    __shared__ float Wsh[64][132];
    const int tid = threadIdx.x;

    if (blockIdx.x >= 256) {
        // ---- forcing branch: (P,E,T1,T2) -> (Ps,Pl,E,relu(Ta)) ----
        int i = (blockIdx.x - 256) * 256 + tid;   // exactly NT*NS = 2920*256
        float4 v = ((const float4*)x)[i];
        float P = v.x, E = v.y, T1 = v.z, T2 = v.w;
        float Ta = 0.5f * (T1 + T2);
        float rP;
        if (T2 <= 0.0f)       rP = 0.0f;          // mask0 wins (applied last in ref)
        else if (T1 >= 0.0f)  rP = 1.0f;
        else                  rP = 1.0f - acosf((T1 + T2) / (T2 - T1)) * (1.0f / 3.1415f);
        float Ps = (1.0f - rP) * P;
        float Pl = rP * P;
        ((float4*)f)[i] = make_float4(Ps, Pl, E, fmaxf(Ta, 0.0f));
        return;
    }

    // ---- gemm branch: w = xc @ W^T + b; 64x64 tile, K=128 in LDS ----
    const int sTile = (blockIdx.x >> 3) * 64;                // 32 s-tiles
    const int by = blockIdx.x & 7;
    const int jt = (by >= 2) ? by + 1 : by;                  // skip unused j-tile 2
    const int jTile = jt * 64;

    for (int i = 0; i < 8; i++) {
        int f4  = tid + i * 256;
        int row = f4 >> 5;
        int c4  = (f4 & 31) * 4;
        float4 v = ((const float4*)(xc + (size_t)(sTile + row) * NG))[f4 & 31];
        xcs[row][c4] = v.x; xcs[row][c4 + 1] = v.y; xcs[row][c4 + 2] = v.z; xcs[row][c4 + 3] = v.w;
        int jr = jTile + row;
        float4 wv = make_float4(0.f, 0.f, 0.f, 0.f);
        if (jr < NW) wv = ((const float4*)(Wm + (size_t)jr * NG))[f4 & 31];
        Wsh[row][c4] = wv.x; Wsh[row][c4 + 1] = wv.y; Wsh[row][c4 + 2] = wv.z; Wsh[row][c4 + 3] = wv.w;
    }
    __syncthreads();

    const int tx = tid & 15, ty = tid >> 4;
    float acc[4][4] = {};
#pragma unroll 4
    for (int k = 0; k < 128; k++) {
        float a0 = xcs[ty][k], a1 = xcs[ty + 16][k], a2 = xcs[ty + 32][k], a3 = xcs[ty + 48][k];
        float b0 = Wsh[tx][k], b1 = Wsh[tx + 16][k], b2 = Wsh[tx + 32][k], b3 = Wsh[tx + 48][k];
        acc[0][0] += a0 * b0; acc[0][1] += a0 * b1; acc[0][2] += a0 * b2; acc[0][3] += a0 * b3;
        acc[1][0] += a1 * b0; acc[1][1] += a1 * b1; acc[1][2] += a1 * b2; acc[1][3] += a1 * b3;
        acc[2][0] += a2 * b0; acc[2][1] += a2 * b1; acc[2][2] += a2 * b2; acc[2][3] += a2 * b3;
        acc[3][0] += a3 * b0; acc[3][1] += a3 * b1; acc[3][2] += a3 * b2; acc[3][3] += a3 * b3;
    }
#pragma unroll
    for (int i = 0; i < 4; i++) {
        int s = sTile + ty + 16 * i;
#pragma unroll
        for (int j = 0; j < 4; j++) {
            int jj = jTile + tx + 16 * j;
            if (jj < NW) w[(size_t)s * WSTR + jj] = acc[i][j] + bv[jj];
        }
    }
}

// ---------------- Kernel C: scan, one site per wave ---------------------------
// Forcing loads: uniform SGPR base + laundered 32-bit rolling byte offsets ->
// global_load_dwordx4 saddr+voffset, 1 v_add_u32 per step, vmcnt domain only.
// Folded algebra: G2=fma(m1,k1*kb,H2), H1=min(fma(m1,-k1,G1),gl) (Q1a removed).
// 32-step superblocks fully unrolled; per-wave [64][33] LDS tile;
// transpose-reduce every 32 steps (imm-offset ds_read_b32, no cross-lane).
template <bool PRE>
__global__ __launch_bounds__(256) void scan_kernel(const float* __restrict__ fx,
                                                   const float* __restrict__ w,
                                                   float* __restrict__ Y) {
    __shared__ float ybuf[4][64][33];   // 33,792 B per block
    const int wave = threadIdx.x >> 6;
    const int lane = threadIdx.x & 63;
    const int s = blockIdx.x * 4 + wave;
    const float* wr = w + (size_t)s * WSTR;

    // gate parameters (lane = hidden unit) — scalar loads OK (setup only)
    float gm = __expf(wr[lane]) + 1.0f;
    float geN = -2.0f * sigmoidf_(wr[64 + lane]);
    float k0 = sigmoidf_(wr[192 + lane]);
    float w4 = wr[256 + lane];
    float k1 = sigmoidf_(w4);
    float k2 = sigmoidf_(wr[320 + lane]);
    float gl = __expf(wr[384 + lane]);
    float kb = sigmoidf_(wr[448 + lane]) * 0.1f;
    float wl = wr[512];
    float qb = fmaxf(wl, 0.0f) * (1.0f / (float)NH);
    float vi = sigmoidf_(wl);

    // softmax over lanes -> ga
    float m = w4;
#pragma unroll
    for (int off = 32; off; off >>= 1) m = fmaxf(m, __shfl_xor(m, off));
    float ex = __expf(w4 - m);
    float sum = ex;
#pragma unroll
    for (int off = 32; off; off >>= 1) sum += __shfl_xor(sum, off);
    float ga = ex / sum;

    // folded coefficients
    float c0   = k0 * ga;
    float c1   = k1 * (1.0f - kb) * ga;
    float c2   = k2 * ga;
    float k0c  = 1.0f - k0;
    float k2c  = 1.0f - k2;
    float glN  = -gl;
    float viC  = 1.0f - vi;
    float k1kb = k1 * kb;    // G2 = fma(m1, k1kb, H2)
    float k1N  = -k1;        // H1 = min(fma(m1, k1N, G1), gl)

    float S0 = 0.f, H0 = 0.f, H1 = 0.f, H2 = 0.f;

    // Forcing loads: keep base UNIFORM (SGPR pair) and launder only the
    // 32-bit byte offset into a VGPR -> saddr+voffset global_load_dwordx4,
    // vmcnt domain (never collides with the per-step ds_write's lgkmcnt).
    const char* fb = (const char*)fx;
    unsigned off0 = (unsigned)s * 16u;
    asm volatile("" : "+v"(off0));
    unsigned offs[8];
    float4 vbuf[8];
#pragma unroll
    for (int b = 0; b < 8; b++) {
        offs[b] = off0 + (unsigned)(b * NS * 16);
        vbuf[b] = *(const float4*)(fb + offs[b]);
        offs[b] += 8u * NS * 16u;           // next use: t = b + 8
    }

    float* wp = &ybuf[wave][lane][0];                           // write: row h=lane
    const float* rp = &ybuf[wave][(lane >> 5) << 5][lane & 31]; // read: column

#define STEP_COMP(vv, tl)                                                      \
    {                                                                          \
        float Ps, Pl, E, TaR;                                                  \
        if (PRE) { Ps = vv.x; Pl = vv.y; E = vv.z; TaR = vv.w; }               \
        else {                                                                 \
            float P = vv.x; E = vv.y;                                          \
            float T1 = vv.z, T2 = vv.w;                                        \
            float Ta = 0.5f * (T1 + T2);                                       \
            float rP;                                                          \
            if (T2 <= 0.0f)      rP = 0.0f;                                    \
            else if (T1 >= 0.0f) rP = 1.0f;                                    \
            else rP = 1.0f - acosf((T1 + T2) / (T2 - T1)) * (1.0f / 3.1415f);  \
            Ps = (1.0f - rP) * P; Pl = rP * P; TaR = fmaxf(Ta, 0.0f);          \
        }                                                                      \
        float S   = S0 + Ps;                                                   \
        float Sm  = fminf(S0, gm * TaR);                                       \
        S0 = S - Sm;                                                           \
        float G1  = fmaxf(H1 + Sm + fmaf(E, geN, Pl * vi), 0.0f);              \
        float G0  = fmaxf(H0 + G1 + fmaf(Pl, viC, glN), 0.0f);                 \
        float m1  = fminf(G1, gl);                                             \
        float G2  = fmaf(m1, k1kb, H2);                                        \
        wp[tl] = fmaf(G0, c0, fmaf(m1, c1, G2 * c2));                          \
        H0 = G0 * k0c;                                                         \
        H1 = fminf(fmaf(m1, k1N, G1), gl);                                     \
        H2 = G2 * k2c;                                                         \
    }

#define TRRED(t0)                                                              \
    {                                                                          \
        float a0 = 0.f, a1 = 0.f, a2 = 0.f, a3 = 0.f;                          \
        _Pragma("unroll")                                                      \
        for (int j = 0; j < 32; j += 4) {                                      \
            a0 += rp[(size_t)j * 33];                                          \
            a1 += rp[(size_t)(j + 1) * 33];                                    \
            a2 += rp[(size_t)(j + 2) * 33];                                    \
            a3 += rp[(size_t)(j + 3) * 33];                                    \
        }                                                                      \
        float part = (a0 + a1) + (a2 + a3);                                    \
        float full = part + __shfl_xor(part, 32);                              \
        int t = (t0) + (lane & 31);                                            \
        if (lane < 32 && t < NT) Y[(size_t)t * NS + s] = full + qb;            \
    }

    // superblocks 0..10: prefetch t0+tl+8 <= 359 < NT, rolling offsets
    for (int sb = 0; sb < 11; ++sb) {
#pragma unroll
        for (int tl = 0; tl < 32; ++tl) {
            float4 v = vbuf[tl & 7];
            vbuf[tl & 7] = *(const float4*)(fb + offs[tl & 7]);  // prefetch
            offs[tl & 7] += 8u * NS * 16u;
            STEP_COMP(v, tl);
        }
        TRRED(sb * 32);
    }
    // tail superblock (t0=352): steps 352..383; stores masked to t<365;
    // prefetch offsets computed fresh with clamped t (no OOB in any path)
    {
        const int t0 = 352;
#pragma unroll
        for (int tl = 0; tl < 32; ++tl) {
            float4 v = vbuf[tl & 7];
            int tn = t0 + tl + 8; tn = tn < NT ? tn : NT - 1;
            vbuf[tl & 7] = *(const float4*)(fb + (off0 + (unsigned)(tn * NS * 16)));
            STEP_COMP(v, tl);
        }
        TRRED(t0);
    }
#undef STEP_COMP
#undef TRRED
}

extern "C" void kernel_launch(void* const* d_in, const int* in_sizes, int n_in,
                              void* d_out, int out_size, void* d_ws, size_t ws_size,
                              hipStream_t stream) {
    const float* x  = (const float*)d_in[0];   // [NT, NS, 4]
    const float* xc = (const float*)d_in[1];   // [NS, NG]
    const float* Wm = (const float*)d_in[2];   // [NW, NG]
    const float* bv = (const float*)d_in[3];   // [NW]
    float* out = (float*)d_out;                // [NT, NS] fp32

    float* wbuf = (float*)d_ws;                                 // NS*WSTR floats
    size_t wbytes = (size_t)NS * WSTR * sizeof(float);          // 4,259,840 B
    float* fbuf = (float*)((char*)d_ws + wbytes);               // NT*NS float4
    size_t need = wbytes + (size_t)NT * NS * 4 * sizeof(float); // ~16.2 MB

    if (ws_size >= need) {
        prep_kernel<<<256 + (NT * NS) / 256, 256, 0, stream>>>(xc, Wm, bv, wbuf, x, fbuf);
        scan_kernel<true><<<NS / 4, 256, 0, stream>>>(fbuf, wbuf, out);
    } else {
        prep_kernel<<<256, 256, 0, stream>>>(xc, Wm, bv, wbuf, x, fbuf);  // gemm only
        scan_kernel<false><<<NS / 4, 256, 0, stream>>>(x, wbuf, out);
    }
}